// Round 12
// baseline (123.388 us; speedup 1.0000x reference)
//
#include <hip/hip_runtime.h>

#define B_ 32
#define T_ 2048
#define C_ 64
#define NP_ 2060          // unique p positions per batch
#define MSTRIDE 144       // floats per 12x12 matrix in global ws (E)
#define LSTRIDE 148       // padded LDS stride
#define MBS 148           // mbuf stride (floats) for transpose buffer

typedef short short8_t __attribute__((ext_vector_type(8)));   // 8 bf16 (4 VGPR)
typedef float f32x4 __attribute__((ext_vector_type(4)));

__device__ __forceinline__ unsigned short f2bf(float f) {
  unsigned u = __float_as_uint(f);
  return (unsigned short)((u + 0x7FFFu + ((u >> 16) & 1u)) >> 16);
}
__device__ __forceinline__ float bf2f(unsigned short s) {
  return __uint_as_float(((unsigned)s) << 16);
}

// ------------------------------------------------------------------
// Quad-lane DPP broadcast + register matmul (validated rounds 2-11)
// ------------------------------------------------------------------
template <int Q>
__device__ __forceinline__ float qb(float v) {
  return __int_as_float(
      __builtin_amdgcn_mov_dpp(__float_as_int(v), Q * 0x55, 0xf, 0xf, true));
}

template <bool ACC>
__device__ __forceinline__ void qmm_t(const float a[3][12], const float b[3][12],
                                      float c[3][12]) {
  if (!ACC) {
#pragma unroll
    for (int i = 0; i < 3; ++i)
#pragma unroll
      for (int j = 0; j < 12; ++j) c[i][j] = 0.f;
  }
#define QMM_K(OWNER, E)                                                  \
  {                                                                      \
    float bk[12];                                                        \
    _Pragma("unroll")                                                    \
    for (int j = 0; j < 12; ++j) bk[j] = qb<OWNER>(b[E][j]);             \
    _Pragma("unroll")                                                    \
    for (int i = 0; i < 3; ++i) {                                        \
      const float av = a[i][3 * OWNER + E];                              \
      _Pragma("unroll")                                                  \
      for (int j = 0; j < 12; ++j) c[i][j] = fmaf(av, bk[j], c[i][j]);   \
    }                                                                    \
  }
  QMM_K(0, 0) QMM_K(0, 1) QMM_K(0, 2)
  QMM_K(1, 0) QMM_K(1, 1) QMM_K(1, 2)
  QMM_K(2, 0) QMM_K(2, 1) QMM_K(2, 2)
  QMM_K(3, 0) QMM_K(3, 1) QMM_K(3, 2)
#undef QMM_K
}
__device__ __forceinline__ void qmm(const float a[3][12], const float b[3][12],
                                    float c[3][12]) { qmm_t<false>(a, b, c); }
__device__ __forceinline__ void qmma(const float a[3][12], const float b[3][12],
                                     float c[3][12]) { qmm_t<true>(a, b, c); }

// ------------------------------------------------------------------
// K12 (fused): MFMA-build of 64 scaled M's -> LDS transpose -> per-quad
// register expm (PS-6 + 5 squarings) -> E to global.
// 256 threads = 4 waves (16 p's each, MFMA) = 64 quads (1 matrix each, expm).
// ------------------------------------------------------------------
__global__ __launch_bounds__(256) void k12_fused(const float* __restrict__ x,
                                                 const float* __restrict__ A,
                                                 float* __restrict__ E) {
  __shared__ float smem[64 * MBS];        // 37888 B; aliases askw during MFMA
  unsigned int* askw = (unsigned int*)smem;  // 9216 u32 = 36864 B
  const int b = blockIdx.y;
  const int p0 = blockIdx.x * 64;
  const int tid = threadIdx.x;
  const float sc = 1.0f / 32.0f;

  // ---- phase 1: stage split ask (bf16 hi/lo, frag-ready) ----
  for (int P = tid; P < 4608; P += 256) {
    const int j2 = P & 3;
    const int col = (P >> 2) & 15;
    const int koct = (P >> 6) & 3;
    const int rest = P >> 8;            // 0..17
    const int tile = rest % 9;
    const int ks = rest / 9;
    const int e = tile * 16 + col;      // < 144
    const int h = e / 12, w = e - h * 12;
    const int c0 = ks * 32 + koct * 8 + j2 * 2;
    const float v0 = (A[c0 * 144 + e] - A[c0 * 144 + w * 12 + h]) * sc;
    const float v1 = (A[(c0 + 1) * 144 + e] - A[(c0 + 1) * 144 + w * 12 + h]) * sc;
    const unsigned short h0 = f2bf(v0), h1 = f2bf(v1);
    const unsigned short l0 = f2bf(v0 - bf2f(h0)), l1 = f2bf(v1 - bf2f(h1));
    const int widx = (((ks * 9 + tile) * 4 + koct) * 16 + col) * 4 + j2;
    askw[widx] = ((unsigned)h1 << 16) | h0;
    askw[4608 + widx] = ((unsigned)l1 << 16) | l0;
  }

  // ---- A-frags: dx rows (bf16 hi/lo) ----
  const int wv = tid >> 6;
  const int lane = tid & 63;
  const int mrow = lane & 15;
  const int koct = lane >> 4;
  {
    const int p = p0 + wv * 16 + mrow;
    const int i1 = min(max(p - 7, 0), T_ - 1);
    const int i2 = min(max(p - 5, 0), T_ - 1);
    const float* xb = x + (size_t)b * T_ * C_;
    short8_t ah[2], al[2];
#pragma unroll
    for (int ks = 0; ks < 2; ++ks) {
      const int c0 = ks * 32 + koct * 8;
      const float4 u1a = *(const float4*)(xb + (size_t)i1 * C_ + c0);
      const float4 u1b = *(const float4*)(xb + (size_t)i1 * C_ + c0 + 4);
      const float4 u2a = *(const float4*)(xb + (size_t)i2 * C_ + c0);
      const float4 u2b = *(const float4*)(xb + (size_t)i2 * C_ + c0 + 4);
      float d[8];
      d[0] = u2a.x - u1a.x; d[1] = u2a.y - u1a.y;
      d[2] = u2a.z - u1a.z; d[3] = u2a.w - u1a.w;
      d[4] = u2b.x - u1b.x; d[5] = u2b.y - u1b.y;
      d[6] = u2b.z - u1b.z; d[7] = u2b.w - u1b.w;
#pragma unroll
      for (int j = 0; j < 8; ++j) {
        const unsigned short hs = f2bf(d[j]);
        ah[ks][j] = (short)hs;
        al[ks][j] = (short)f2bf(d[j] - bf2f(hs));
      }
    }
    __syncthreads();   // askw staged

    // ---- phase 2: MFMA, all 9 tiles into regs ----
    f32x4 accs[9];
    const int dcol = lane & 15;
    const char* lds = (const char*)askw;
#pragma unroll
    for (int tile = 0; tile < 9; ++tile) {
      f32x4 acc = {0.f, 0.f, 0.f, 0.f};
#pragma unroll
      for (int ks = 0; ks < 2; ++ks) {
        const int fb = (((ks * 9 + tile) * 4 + koct) * 16 + dcol) * 16;
        const short8_t bh = *(const short8_t*)(lds + fb);
        const short8_t bl = *(const short8_t*)(lds + 18432 + fb);
        acc = __builtin_amdgcn_mfma_f32_16x16x32_bf16(ah[ks], bh, acc, 0, 0, 0);
        acc = __builtin_amdgcn_mfma_f32_16x16x32_bf16(ah[ks], bl, acc, 0, 0, 0);
        acc = __builtin_amdgcn_mfma_f32_16x16x32_bf16(al[ks], bh, acc, 0, 0, 0);
      }
      accs[tile] = acc;
    }
    __syncthreads();   // all askw reads done -> smem reusable as mbuf

    // ---- phase 3: transpose D-layout -> matrix-major in LDS ----
    // lane writes M[nl = wv*16+(lane>>4)*4+reg][tile*16+dcol]
    const int nlbase = wv * 16 + (lane >> 4) * 4;
#pragma unroll
    for (int reg = 0; reg < 4; ++reg) {
      float* mrow_ = smem + (nlbase + reg) * MBS;
#pragma unroll
      for (int tile = 0; tile < 9; ++tile)
        mrow_[tile * 16 + dcol] = accs[tile][reg];
    }
  }
  __syncthreads();

  // ---- phase 4: per-quad expm ----
  const int q = tid >> 2;      // matrix 0..63
  const int r = tid & 3;       // rows 3r..3r+2
  float a[3][12], t2[3][12], t3[3][12];
  {
    const float* mp = smem + q * MBS;
#pragma unroll
    for (int i = 0; i < 3; ++i) {
      const float* rp = mp + (3 * r + i) * 12;
      float4 v0 = *(const float4*)(rp + 0);
      float4 v1 = *(const float4*)(rp + 4);
      float4 v2 = *(const float4*)(rp + 8);
      a[i][0] = v0.x; a[i][1] = v0.y; a[i][2]  = v0.z; a[i][3]  = v0.w;
      a[i][4] = v1.x; a[i][5] = v1.y; a[i][6]  = v1.z; a[i][7]  = v1.w;
      a[i][8] = v2.x; a[i][9] = v2.y; a[i][10] = v2.z; a[i][11] = v2.w;
    }
  }

  qmm(a, a, t2);      // M2
  qmm(t2, a, t3);     // M3
#pragma unroll
  for (int i = 0; i < 3; ++i)
#pragma unroll
    for (int j = 0; j < 12; ++j) {
      const float av = a[i][j], t2v = t2[i][j], t3v = t3[i][j];
      t2[i][j] = av + t2v * 0.5f + t3v * (1.0f / 6.0f) +
                 ((j == 3 * r + i) ? 1.0f : 0.0f);
      a[i][j] = av * (1.0f / 24.0f) + t2v * (1.0f / 120.0f) +
                t3v * (1.0f / 720.0f);
    }
  qmma(t3, a, t2);    // t2 += M3*W

  qmm(t2, t2, t3);
  qmm(t3, t3, t2);
  qmm(t2, t2, t3);
  qmm(t3, t3, t2);
  qmm(t2, t2, t3);    // E in t3

  // ---- phase 5: E -> global (k2's proven store pattern) ----
  const int p = p0 + q;
  if (p < NP_) {
    float* gp = E + ((size_t)b * NP_ + p) * MSTRIDE + 36 * r;
#pragma unroll
    for (int i = 0; i < 3; ++i)
#pragma unroll
      for (int q4 = 0; q4 < 3; ++q4)
        *(float4*)(gp + i * 12 + q4 * 4) =
            make_float4(t3[i][q4 * 4 + 0], t3[i][q4 * 4 + 1],
                        t3[i][q4 * 4 + 2], t3[i][q4 * 4 + 3]);
  }
}

// ------------------------------------------------------------------
// K3: chain of 7 E's per window + passthrough (round-10 version, 48 us)
// ------------------------------------------------------------------
__global__ __launch_bounds__(256) void k3_chain(const float* __restrict__ E,
                                                const float* __restrict__ x,
                                                float* __restrict__ out) {
  __shared__ float eb[76][LSTRIDE];
  const int b = blockIdx.y;
  const int t0 = blockIdx.x * 64;
  const float* src = E + ((size_t)b * NP_ + t0) * MSTRIDE;
  for (int i = threadIdx.x; i < 76 * 36; i += 256) {
    int m = i / 36, q = i - m * 36;
    *(float4*)(&eb[m][q * 4]) = *(const float4*)(src + (size_t)m * MSTRIDE + q * 4);
  }
  __syncthreads();

  const int r = threadIdx.x & 3;
  const int tl = threadIdx.x >> 2;
  const int t = t0 + tl;

  float z[3][12], c[3][12];
#pragma unroll
  for (int i = 0; i < 3; ++i) {
    const float* zp = &eb[tl][(3 * r + i) * 12];
    float4 v0 = *(const float4*)(zp + 0);
    float4 v1 = *(const float4*)(zp + 4);
    float4 v2 = *(const float4*)(zp + 8);
    z[i][0] = v0.x; z[i][1] = v0.y; z[i][2]  = v0.z; z[i][3]  = v0.w;
    z[i][4] = v1.x; z[i][5] = v1.y; z[i][6]  = v1.z; z[i][7]  = v1.w;
    z[i][8] = v2.x; z[i][9] = v2.y; z[i][10] = v2.z; z[i][11] = v2.w;
  }

#define CHAIN_STEP(SRC, DST, J)                                          \
  {                                                                      \
    float bb[3][12];                                                     \
    _Pragma("unroll")                                                    \
    for (int i = 0; i < 3; ++i) {                                        \
      const float* ep = &eb[tl + 2 * (J)][(3 * r + i) * 12];             \
      float4 v0 = *(const float4*)(ep + 0);                              \
      float4 v1 = *(const float4*)(ep + 4);                              \
      float4 v2 = *(const float4*)(ep + 8);                              \
      bb[i][0] = v0.x; bb[i][1] = v0.y; bb[i][2]  = v0.z; bb[i][3]  = v0.w; \
      bb[i][4] = v1.x; bb[i][5] = v1.y; bb[i][6]  = v1.z; bb[i][7]  = v1.w; \
      bb[i][8] = v2.x; bb[i][9] = v2.y; bb[i][10] = v2.z; bb[i][11] = v2.w; \
    }                                                                    \
    qmm(SRC, bb, DST);                                                   \
  }
  CHAIN_STEP(z, c, 1)
  CHAIN_STEP(c, z, 2)
  CHAIN_STEP(z, c, 3)
  CHAIN_STEP(c, z, 4)
  CHAIN_STEP(z, c, 5)
  CHAIN_STEP(c, z, 6)
#undef CHAIN_STEP

  const size_t obase = ((size_t)b * T_ + t) * 208;
#pragma unroll
  for (int i = 0; i < 3; ++i) {
    const int row = 3 * r + i;
    *(float4*)(out + obase + row * 12 + 0) = make_float4(z[i][0], z[i][1], z[i][2],  z[i][3]);
    *(float4*)(out + obase + row * 12 + 4) = make_float4(z[i][4], z[i][5], z[i][6],  z[i][7]);
    *(float4*)(out + obase + row * 12 + 8) = make_float4(z[i][8], z[i][9], z[i][10], z[i][11]);
  }
  const int xi = min(max(t - 7, 0), T_ - 1);
  const float* xr = x + ((size_t)b * T_ + xi) * C_ + 16 * r;
#pragma unroll
  for (int q = 0; q < 4; ++q) {
    *(float4*)(out + obase + 144 + 16 * r + q * 4) = *(const float4*)(xr + q * 4);
  }
}

// ------------------------------------------------------------------
extern "C" void kernel_launch(void* const* d_in, const int* in_sizes, int n_in,
                              void* d_out, int out_size, void* d_ws, size_t ws_size,
                              hipStream_t stream) {
  (void)in_sizes; (void)n_in; (void)out_size;
  const float* x = (const float*)d_in[0];
  const float* A = (const float*)d_in[1];
  float* out = (float*)d_out;
  float* E = (float*)d_ws;

  const size_t need = (size_t)B_ * NP_ * MSTRIDE * sizeof(float);  // ~38 MB
  if (ws_size < need) return;

  k12_fused<<<dim3(33, B_), 256, 0, stream>>>(x, A, E);
  k3_chain<<<dim3(T_ / 64, B_), 256, 0, stream>>>(E, x, out);
}

// Round 13
// 104.401 us; speedup vs baseline: 1.1819x; 1.1819x over previous
//
#include <hip/hip_runtime.h>

#define B_ 32
#define T_ 2048
#define C_ 64
#define NP_ 2060          // unique p positions per batch
#define MSTRIDE 144       // floats per 12x12 matrix in global ws

typedef short short8_t __attribute__((ext_vector_type(8)));   // 8 bf16 (4 VGPR)
typedef float f32x4 __attribute__((ext_vector_type(4)));

__device__ __forceinline__ unsigned short f2bf(float f) {
  unsigned u = __float_as_uint(f);
  return (unsigned short)((u + 0x7FFFu + ((u >> 16) & 1u)) >> 16);
}
__device__ __forceinline__ float bf2f(unsigned short s) {
  return __uint_as_float(((unsigned)s) << 16);
}

// ------------------------------------------------------------------
// K1 (MFMA): M[b][p][e] = sum_c dx[p][c] * ask[c][e], scaled 2^-4.
// (round-10 validated; only the scale changed: s=4 squarings in k2)
// ------------------------------------------------------------------
__global__ __launch_bounds__(256) void k1_mfma(const float* __restrict__ x,
                                               const float* __restrict__ A,
                                               float* __restrict__ M) {
  __shared__ unsigned int askw[9216];   // 36 KB
  const int b = blockIdx.y;
  const int p0 = blockIdx.x * 64;
  const int tid = threadIdx.x;
  const float sc = 1.0f / 16.0f;        // 2^-4

  for (int P = tid; P < 4608; P += 256) {
    const int j2 = P & 3;
    const int col = (P >> 2) & 15;
    const int koct = (P >> 6) & 3;
    const int rest = P >> 8;            // 0..17
    const int tile = rest % 9;
    const int ks = rest / 9;
    const int e = tile * 16 + col;      // < 144
    const int h = e / 12, w = e - h * 12;
    const int c0 = ks * 32 + koct * 8 + j2 * 2;
    const float v0 = (A[c0 * 144 + e] - A[c0 * 144 + w * 12 + h]) * sc;
    const float v1 = (A[(c0 + 1) * 144 + e] - A[(c0 + 1) * 144 + w * 12 + h]) * sc;
    const unsigned short h0 = f2bf(v0), h1 = f2bf(v1);
    const unsigned short l0 = f2bf(v0 - bf2f(h0)), l1 = f2bf(v1 - bf2f(h1));
    const int widx = (((ks * 9 + tile) * 4 + koct) * 16 + col) * 4 + j2;
    askw[widx] = ((unsigned)h1 << 16) | h0;
    askw[4608 + widx] = ((unsigned)l1 << 16) | l0;
  }
  __syncthreads();

  const int wv = tid >> 6;
  const int lane = tid & 63;
  const int mrow = lane & 15;
  const int koct = lane >> 4;
  const int p = p0 + wv * 16 + mrow;
  const int i1 = min(max(p - 7, 0), T_ - 1);
  const int i2 = min(max(p - 5, 0), T_ - 1);
  const float* xb = x + (size_t)b * T_ * C_;

  short8_t ah[2], al[2];
#pragma unroll
  for (int ks = 0; ks < 2; ++ks) {
    const int c0 = ks * 32 + koct * 8;
    const float4 u1a = *(const float4*)(xb + (size_t)i1 * C_ + c0);
    const float4 u1b = *(const float4*)(xb + (size_t)i1 * C_ + c0 + 4);
    const float4 u2a = *(const float4*)(xb + (size_t)i2 * C_ + c0);
    const float4 u2b = *(const float4*)(xb + (size_t)i2 * C_ + c0 + 4);
    float d[8];
    d[0] = u2a.x - u1a.x; d[1] = u2a.y - u1a.y;
    d[2] = u2a.z - u1a.z; d[3] = u2a.w - u1a.w;
    d[4] = u2b.x - u1b.x; d[5] = u2b.y - u1b.y;
    d[6] = u2b.z - u1b.z; d[7] = u2b.w - u1b.w;
#pragma unroll
    for (int j = 0; j < 8; ++j) {
      const unsigned short hs = f2bf(d[j]);
      ah[ks][j] = (short)hs;
      al[ks][j] = (short)f2bf(d[j] - bf2f(hs));
    }
  }

  float* Mb = M + (size_t)b * NP_ * MSTRIDE;
  const int dcol = lane & 15;
  const int pbase = p0 + wv * 16 + (lane >> 4) * 4;
  const char* lds = (const char*)askw;
#pragma unroll
  for (int tile = 0; tile < 9; ++tile) {
    f32x4 acc = {0.f, 0.f, 0.f, 0.f};
#pragma unroll
    for (int ks = 0; ks < 2; ++ks) {
      const int fb = (((ks * 9 + tile) * 4 + koct) * 16 + dcol) * 16;  // byte
      const short8_t bh = *(const short8_t*)(lds + fb);
      const short8_t bl = *(const short8_t*)(lds + 18432 + fb);
      acc = __builtin_amdgcn_mfma_f32_16x16x32_bf16(ah[ks], bh, acc, 0, 0, 0);
      acc = __builtin_amdgcn_mfma_f32_16x16x32_bf16(ah[ks], bl, acc, 0, 0, 0);
      acc = __builtin_amdgcn_mfma_f32_16x16x32_bf16(al[ks], bh, acc, 0, 0, 0);
    }
#pragma unroll
    for (int reg = 0; reg < 4; ++reg) {
      const int pr = pbase + reg;
      if (pr < NP_) Mb[(size_t)pr * MSTRIDE + tile * 16 + dcol] = acc[reg];
    }
  }
}

// ------------------------------------------------------------------
// Quad-lane DPP broadcast + register matmul (validated rounds 2-12)
// ------------------------------------------------------------------
template <int Q>
__device__ __forceinline__ float qb(float v) {
  return __int_as_float(
      __builtin_amdgcn_mov_dpp(__float_as_int(v), Q * 0x55, 0xf, 0xf, true));
}

template <bool ACC>
__device__ __forceinline__ void qmm_t(const float a[3][12], const float b[3][12],
                                      float c[3][12]) {
  if (!ACC) {
#pragma unroll
    for (int i = 0; i < 3; ++i)
#pragma unroll
      for (int j = 0; j < 12; ++j) c[i][j] = 0.f;
  }
#define QMM_K(OWNER, E)                                                  \
  {                                                                      \
    float bk[12];                                                        \
    _Pragma("unroll")                                                    \
    for (int j = 0; j < 12; ++j) bk[j] = qb<OWNER>(b[E][j]);             \
    _Pragma("unroll")                                                    \
    for (int i = 0; i < 3; ++i) {                                        \
      const float av = a[i][3 * OWNER + E];                              \
      _Pragma("unroll")                                                  \
      for (int j = 0; j < 12; ++j) c[i][j] = fmaf(av, bk[j], c[i][j]);   \
    }                                                                    \
  }
  QMM_K(0, 0) QMM_K(0, 1) QMM_K(0, 2)
  QMM_K(1, 0) QMM_K(1, 1) QMM_K(1, 2)
  QMM_K(2, 0) QMM_K(2, 1) QMM_K(2, 2)
  QMM_K(3, 0) QMM_K(3, 1) QMM_K(3, 2)
#undef QMM_K
}
__device__ __forceinline__ void qmm(const float a[3][12], const float b[3][12],
                                    float c[3][12]) { qmm_t<false>(a, b, c); }
__device__ __forceinline__ void qmma(const float a[3][12], const float b[3][12],
                                     float c[3][12]) { qmm_t<true>(a, b, c); }

// ------------------------------------------------------------------
// K2: in-place E = expm(16*Min). PS-6 Taylor (3 mults) + 4 squarings.
// ------------------------------------------------------------------
__global__ __launch_bounds__(256) void k2_expm(float* __restrict__ M) {
  const int gq = (blockIdx.x * 256 + threadIdx.x) >> 2;
  const int r = threadIdx.x & 3;
  float* gp = M + (size_t)gq * MSTRIDE + 36 * r;

  float a[3][12], t2[3][12], t3[3][12];
#pragma unroll
  for (int i = 0; i < 3; ++i)
#pragma unroll
    for (int q4 = 0; q4 < 3; ++q4) {
      float4 v = *(const float4*)(gp + i * 12 + q4 * 4);
      a[i][q4 * 4 + 0] = v.x;
      a[i][q4 * 4 + 1] = v.y;
      a[i][q4 * 4 + 2] = v.z;
      a[i][q4 * 4 + 3] = v.w;
    }

  qmm(a, a, t2);      // M2
  qmm(t2, a, t3);     // M3
#pragma unroll
  for (int i = 0; i < 3; ++i)
#pragma unroll
    for (int j = 0; j < 12; ++j) {
      const float av = a[i][j], t2v = t2[i][j], t3v = t3[i][j];
      t2[i][j] = av + t2v * 0.5f + t3v * (1.0f / 6.0f) +
                 ((j == 3 * r + i) ? 1.0f : 0.0f);
      a[i][j] = av * (1.0f / 24.0f) + t2v * (1.0f / 120.0f) +
                t3v * (1.0f / 720.0f);
    }
  qmma(t3, a, t2);    // t2 += M3*W  (degree-6 poly)

  // 4 squarings; E lands in t2
  qmm(t2, t2, t3);
  qmm(t3, t3, t2);
  qmm(t2, t2, t3);
  qmm(t3, t3, t2);

#pragma unroll
  for (int i = 0; i < 3; ++i)
#pragma unroll
    for (int q4 = 0; q4 < 3; ++q4)
      *(float4*)(gp + i * 12 + q4 * 4) =
          make_float4(t2[i][q4 * 4 + 0], t2[i][q4 * 4 + 1],
                      t2[i][q4 * 4 + 2], t2[i][q4 * 4 + 3]);
}

// ------------------------------------------------------------------
// K3 (pair, global-read): one quad computes windows (t, t+2):
//   R = E(t+2)...E(t+12) (5 qmm), Z(t)=E(t)*R, Z(t+2)=R*E(t+14).
// All 64 quads active, 128 windows/block, NO LDS (E is L2/L3-resident),
// no barriers, no bank conflicts. Max p = 1920+125+14 = 2059 = NP_-1.
// ------------------------------------------------------------------
__global__ __launch_bounds__(256) void k3_pair(const float* __restrict__ E,
                                               const float* __restrict__ x,
                                               float* __restrict__ out) {
  const int b = blockIdx.y;
  const int t0 = blockIdx.x * 128;
  const float* Eb = E + (size_t)b * NP_ * MSTRIDE;

  const int r = threadIdx.x & 3;
  const int q = threadIdx.x >> 2;       // quad 0..63
  const int par = q & 1, jj = q >> 1;   // jj 0..31
  const int tloc = 4 * jj + par;        // covers 0..125; +2 -> all 128
  const int t1 = t0 + tloc;

#define LOADB_G(DST, P)                                                  \
  {                                                                      \
    const float* ep = Eb + (size_t)(P) * MSTRIDE + (3 * r) * 12;         \
    _Pragma("unroll")                                                    \
    for (int i = 0; i < 3; ++i) {                                        \
      float4 v0 = *(const float4*)(ep + i * 12 + 0);                     \
      float4 v1 = *(const float4*)(ep + i * 12 + 4);                     \
      float4 v2 = *(const float4*)(ep + i * 12 + 8);                     \
      DST[i][0] = v0.x; DST[i][1] = v0.y; DST[i][2]  = v0.z; DST[i][3]  = v0.w; \
      DST[i][4] = v1.x; DST[i][5] = v1.y; DST[i][6]  = v1.z; DST[i][7]  = v1.w; \
      DST[i][8] = v2.x; DST[i][9] = v2.y; DST[i][10] = v2.z; DST[i][11] = v2.w; \
    }                                                                    \
  }

#define STOREZ(SRCZ, TW)                                                 \
  {                                                                      \
    const size_t obase = ((size_t)b * T_ + (TW)) * 208;                  \
    _Pragma("unroll")                                                    \
    for (int i = 0; i < 3; ++i) {                                        \
      const int row = 3 * r + i;                                         \
      *(float4*)(out + obase + row * 12 + 0) =                           \
          make_float4(SRCZ[i][0], SRCZ[i][1], SRCZ[i][2],  SRCZ[i][3]);  \
      *(float4*)(out + obase + row * 12 + 4) =                           \
          make_float4(SRCZ[i][4], SRCZ[i][5], SRCZ[i][6],  SRCZ[i][7]);  \
      *(float4*)(out + obase + row * 12 + 8) =                           \
          make_float4(SRCZ[i][8], SRCZ[i][9], SRCZ[i][10], SRCZ[i][11]); \
    }                                                                    \
    const int xi = min(max((TW) - 7, 0), T_ - 1);                        \
    const float* xr = x + ((size_t)b * T_ + xi) * C_ + 16 * r;           \
    _Pragma("unroll")                                                    \
    for (int qd = 0; qd < 4; ++qd) {                                     \
      *(float4*)(out + obase + 144 + 16 * r + qd * 4) =                  \
          *(const float4*)(xr + qd * 4);                                 \
    }                                                                    \
  }

  float rr[3][12], cc[3][12], bb[3][12];
  LOADB_G(rr, t1 + 2);                    // R = E(t+2)
  LOADB_G(bb, t1 + 4);  qmm(rr, bb, cc);
  LOADB_G(bb, t1 + 6);  qmm(cc, bb, rr);
  LOADB_G(bb, t1 + 8);  qmm(rr, bb, cc);
  LOADB_G(bb, t1 + 10); qmm(cc, bb, rr);
  LOADB_G(bb, t1 + 12); qmm(rr, bb, cc);  // cc = R = E(t+2)...E(t+12)

  LOADB_G(bb, t1);      qmm(bb, cc, rr);  // Z(t) = E(t)*R
  STOREZ(rr, t1);
  LOADB_G(bb, t1 + 14); qmm(cc, bb, rr);  // Z(t+2) = R*E(t+14)
  STOREZ(rr, t1 + 2);
#undef LOADB_G
#undef STOREZ
}

// ------------------------------------------------------------------
extern "C" void kernel_launch(void* const* d_in, const int* in_sizes, int n_in,
                              void* d_out, int out_size, void* d_ws, size_t ws_size,
                              hipStream_t stream) {
  (void)in_sizes; (void)n_in; (void)out_size;
  const float* x = (const float*)d_in[0];
  const float* A = (const float*)d_in[1];
  float* out = (float*)d_out;
  float* M = (float*)d_ws;

  const size_t need = (size_t)B_ * NP_ * MSTRIDE * sizeof(float);  // ~38 MB
  if (ws_size < need) return;

  k1_mfma<<<dim3(33, B_), 256, 0, stream>>>(x, A, M);
  k2_expm<<<dim3((B_ * NP_ * 4) / 256), 256, 0, stream>>>(M);   // 1030 blocks
  k3_pair<<<dim3(T_ / 128, B_), 256, 0, stream>>>(M, x, out);   // 16 x 32
}